// Round 11
// baseline (721.204 us; speedup 1.0000x reference)
//
#include <hip/hip_runtime.h>

// GraphNN 3-layer weighted-mean GCN. N=100k, E=1M, d=64.
// R8: transform was LDS-pipe-bound (64 b128 reads/node, ~300k cyc/CU floor).
// Fix: weights in VGPRs (128 regs/lane), bf16 LDS bounce for agg/x rows
// (16 b128 broadcast reads/node), direct per-group csr loads (no bpermute).

static constexpr int kD = 64;
typedef unsigned int uint_t;
typedef unsigned short ushort_t;

__device__ __forceinline__ ushort_t f2bf(float f) {
  uint_t u = __float_as_uint(f);
  u += 0x7fffu + ((u >> 16) & 1u);  // RNE
  return (ushort_t)(u >> 16);
}

__global__ __launch_bounds__(256) void k_edge_deg(
    const int* __restrict__ col, const float* __restrict__ ew,
    float* __restrict__ deg, uint_t* __restrict__ cnt, int E) {
  int e = blockIdx.x * 256 + threadIdx.x;
  if (e >= E) return;
  int c = col[e];
  unsafeAtomicAdd(&deg[c], ew[e]);
  atomicAdd(&cnt[c], 1u);
}

__global__ __launch_bounds__(256) void k_node_pre(float* __restrict__ deg, int N) {
  int n = blockIdx.x * 256 + threadIdx.x;
  if (n >= N) return;
  float d = deg[n];
  deg[n] = (d > 0.0f) ? rsqrtf(d) : 0.0f;
}

__global__ __launch_bounds__(256) void k_scanA(
    const uint_t* __restrict__ cnt, uint_t* __restrict__ incl,
    uint_t* __restrict__ bsum, int N) {
  __shared__ uint_t s[256];
  int t = threadIdx.x;
  int i = blockIdx.x * 256 + t;
  uint_t v = (i < N) ? cnt[i] : 0u;
  s[t] = v;
  __syncthreads();
  for (int off = 1; off < 256; off <<= 1) {
    uint_t tv = (t >= off) ? s[t - off] : 0u;
    __syncthreads();
    s[t] += tv;
    __syncthreads();
  }
  if (i < N) incl[i] = s[t];
  if (t == 255) bsum[blockIdx.x] = s[255];
}

__global__ __launch_bounds__(512) void k_scanB(
    const uint_t* __restrict__ bsum, uint_t* __restrict__ boff, int nb) {
  __shared__ uint_t s[512];
  int t = threadIdx.x;
  uint_t v = (t < nb) ? bsum[t] : 0u;
  s[t] = v;
  __syncthreads();
  for (int off = 1; off < 512; off <<= 1) {
    uint_t tv = (t >= off) ? s[t - off] : 0u;
    __syncthreads();
    s[t] += tv;
    __syncthreads();
  }
  if (t < nb) boff[t] = s[t] - v;
}

__global__ __launch_bounds__(256) void k_scanC(
    const uint_t* __restrict__ incl, const uint_t* __restrict__ cnt,
    const uint_t* __restrict__ boff, uint_t* __restrict__ rowptr, int N) {
  int i = blockIdx.x * 256 + threadIdx.x;
  if (i >= N) return;
  uint_t inc = incl[i] + boff[i >> 8];
  rowptr[i] = inc - cnt[i];
  if (i == N - 1) rowptr[N] = inc;
}

__global__ __launch_bounds__(256) void k_fill(
    const int* __restrict__ row, const int* __restrict__ col,
    const float* __restrict__ ew, const float* __restrict__ dis,
    const uint_t* __restrict__ rowptr, uint_t* __restrict__ fillcnt,
    int2* __restrict__ csr, int E) {
  int e = blockIdx.x * 256 + threadIdx.x;
  if (e >= E) return;
  int c = col[e];
  int r = row[e];
  float w = dis[r] * ew[e] * dis[c];
  uint_t pos = atomicAdd(&fillcnt[c], 1u);
  csr[rowptr[c] + pos] = make_int2(r, __float_as_int(w));
}

__global__ __launch_bounds__(256) void k_cvt(
    const float* __restrict__ x, ushort_t* __restrict__ xb, int total) {
  int i = blockIdx.x * 256 + threadIdx.x;
  if (i >= total) return;
  xb[i] = f2bf(x[i]);
}

// ---------- fused layer: VGPR weights, bf16 rows, minimal LDS ----------
// 4 waves/block; lane groups g=0..3 x 16 lanes. Per edge: group loads its
// csr record directly (same-addr in group), gathers uint2 (4 bf16) per lane.
// Cross-group shfl_xor reduce; agg+x bounce through LDS as bf16; transform
// with weights in 128 VGPRs (lane j holds rows j of Wl, Wr).
__global__ __launch_bounds__(256) void k_layer(
    const ushort_t* __restrict__ A, ushort_t* __restrict__ B16,
    float* __restrict__ Bf,
    const int2* __restrict__ csr, const uint_t* __restrict__ rowptr,
    const float* __restrict__ Wl, const float* __restrict__ bl,
    const float* __restrict__ Wr, int N, int relu, int nwaves) {
  __shared__ ushort_t sAggB[4][kD];
  __shared__ ushort_t sXb[4][kD];
  int tid = threadIdx.x;
  int wave = tid >> 6, lane = tid & 63;
  int g = lane >> 4;
  int l16 = lane & 15;

  float4 wl4[16], wr4[16];
#pragma unroll
  for (int k = 0; k < 16; ++k) {
    wl4[k] = *reinterpret_cast<const float4*>(Wl + (size_t)lane * kD + k * 4);
    wr4[k] = *reinterpret_cast<const float4*>(Wr + (size_t)lane * kD + k * 4);
  }
  float bias = bl[lane];

  int gw = blockIdx.x * 4 + wave;
  for (int n = gw; n < N; n += nwaves) {
    uint_t rb = rowptr[n];
    uint_t re = rowptr[n + 1];
    int degc = (int)(re - rb);
    float4 acc = make_float4(0.f, 0.f, 0.f, 0.f);
#define GATHER_STEP(IDX)                                                   \
    { uint_t ix = (IDX);                                                   \
      bool val = ix < re;                                                  \
      int2 er = csr[val ? ix : rb];                                        \
      float ww = val ? __int_as_float(er.y) : 0.0f;                        \
      uint2 q = *reinterpret_cast<const uint2*>(A + (size_t)er.x * kD + l16 * 4); \
      acc.x += ww * __uint_as_float(q.x << 16);                            \
      acc.y += ww * __uint_as_float(q.x & 0xffff0000u);                    \
      acc.z += ww * __uint_as_float(q.y << 16);                            \
      acc.w += ww * __uint_as_float(q.y & 0xffff0000u); }
    for (uint_t s4 = rb + g; s4 < re; s4 += 8) {
      GATHER_STEP(s4)
      GATHER_STEP(s4 + 4)
    }
#undef GATHER_STEP
    acc.x += __shfl_xor(acc.x, 16); acc.y += __shfl_xor(acc.y, 16);
    acc.z += __shfl_xor(acc.z, 16); acc.w += __shfl_xor(acc.w, 16);
    acc.x += __shfl_xor(acc.x, 32); acc.y += __shfl_xor(acc.y, 32);
    acc.z += __shfl_xor(acc.z, 32); acc.w += __shfl_xor(acc.w, 32);
    float ci = (degc > 0) ? (1.0f / (float)degc) : 1.0f;
    if (g == 0) {
      uint_t p0 = (uint_t)f2bf(acc.x * ci) | ((uint_t)f2bf(acc.y * ci) << 16);
      uint_t p1 = (uint_t)f2bf(acc.z * ci) | ((uint_t)f2bf(acc.w * ci) << 16);
      *reinterpret_cast<uint2*>(&sAggB[wave][l16 * 4]) = make_uint2(p0, p1);
    }
    sXb[wave][lane] = A[(size_t)n * kD + lane];
    // wave-local LDS producer/consumer: compiler inserts lgkmcnt waits.
    float o = bias;
#pragma unroll
    for (int k8 = 0; k8 < 8; ++k8) {
      uint4 qa = *reinterpret_cast<const uint4*>(&sAggB[wave][k8 * 8]);
      uint4 qx = *reinterpret_cast<const uint4*>(&sXb[wave][k8 * 8]);
      float4 wla = wl4[k8 * 2], wlb = wl4[k8 * 2 + 1];
      float4 wra = wr4[k8 * 2], wrb = wr4[k8 * 2 + 1];
      o += __uint_as_float(qa.x << 16)         * wla.x;
      o += __uint_as_float(qa.x & 0xffff0000u) * wla.y;
      o += __uint_as_float(qa.y << 16)         * wla.z;
      o += __uint_as_float(qa.y & 0xffff0000u) * wla.w;
      o += __uint_as_float(qa.z << 16)         * wlb.x;
      o += __uint_as_float(qa.z & 0xffff0000u) * wlb.y;
      o += __uint_as_float(qa.w << 16)         * wlb.z;
      o += __uint_as_float(qa.w & 0xffff0000u) * wlb.w;
      o += __uint_as_float(qx.x << 16)         * wra.x;
      o += __uint_as_float(qx.x & 0xffff0000u) * wra.y;
      o += __uint_as_float(qx.y << 16)         * wra.z;
      o += __uint_as_float(qx.y & 0xffff0000u) * wra.w;
      o += __uint_as_float(qx.z << 16)         * wrb.x;
      o += __uint_as_float(qx.z & 0xffff0000u) * wrb.y;
      o += __uint_as_float(qx.w << 16)         * wrb.z;
      o += __uint_as_float(qx.w & 0xffff0000u) * wrb.w;
    }
    if (relu) o = fmaxf(o, 0.0f);
    if (B16) B16[(size_t)n * kD + lane] = f2bf(o);
    else     Bf[(size_t)n * kD + lane] = o;
  }
}

extern "C" void kernel_launch(void* const* d_in, const int* in_sizes, int n_in,
                              void* d_out, int out_size, void* d_ws, size_t ws_size,
                              hipStream_t stream) {
  const float* x   = (const float*)d_in[0];
  const int*   ei  = (const int*)d_in[1];
  const float* ew  = (const float*)d_in[2];
  const float* Wl0 = (const float*)d_in[3];
  const float* bl0 = (const float*)d_in[4];
  const float* Wr0 = (const float*)d_in[5];
  const float* Wl1 = (const float*)d_in[6];
  const float* bl1 = (const float*)d_in[7];
  const float* Wr1 = (const float*)d_in[8];
  const float* Wl2 = (const float*)d_in[9];
  const float* bl2 = (const float*)d_in[10];
  const float* Wr2 = (const float*)d_in[11];
  float* out = (float*)d_out;

  const int N = in_sizes[0] / kD;
  const int E = in_sizes[2];
  const int* row = ei;
  const int* col = ei + E;

  const int nb256 = (N + 255) / 256;

  char* p = (char*)d_ws;
  int2*     csr     = (int2*)p;     p += (size_t)E * sizeof(int2);
  ushort_t* xb      = (ushort_t*)p; p += (size_t)N * kD * sizeof(ushort_t);
  ushort_t* h1      = (ushort_t*)p; p += (size_t)N * kD * sizeof(ushort_t);
  ushort_t* h2      = (ushort_t*)p; p += (size_t)N * kD * sizeof(ushort_t);
  float*    deg     = (float*)p;    p += (size_t)N * sizeof(float);
  uint_t*   cnt     = (uint_t*)p;   p += (size_t)N * sizeof(uint_t);
  uint_t*   fillcnt = (uint_t*)p;   p += (size_t)N * sizeof(uint_t);
  uint_t*   rowptr  = (uint_t*)p;   p += (size_t)(N + 1) * sizeof(uint_t);
  uint_t*   incl    = (uint_t*)p;   p += (size_t)N * sizeof(uint_t);
  uint_t*   bsum    = (uint_t*)p;   p += (size_t)nb256 * sizeof(uint_t);
  uint_t*   boff    = (uint_t*)p;

  const int eb = (E + 255) / 256;

  hipMemsetAsync(deg, 0, 3 * (size_t)N * sizeof(float), stream);
  k_edge_deg<<<eb, 256, 0, stream>>>(col, ew, deg, cnt, E);
  k_node_pre<<<nb256, 256, 0, stream>>>(deg, N);
  k_scanA<<<nb256, 256, 0, stream>>>(cnt, incl, bsum, N);
  k_scanB<<<1, 512, 0, stream>>>(bsum, boff, nb256);
  k_scanC<<<nb256, 256, 0, stream>>>(incl, cnt, boff, rowptr, N);
  k_fill<<<eb, 256, 0, stream>>>(row, col, ew, deg, rowptr, fillcnt, csr, E);
  k_cvt<<<(N * kD + 255) / 256, 256, 0, stream>>>(x, xb, N * kD);

  const int blocks = 2048;           // 4 waves each -> 8192 waves
  const int nwaves = blocks * 4;
  k_layer<<<blocks, 256, 0, stream>>>(xb, h1, nullptr, csr, rowptr, Wl0, bl0, Wr0, N, 1, nwaves);
  k_layer<<<blocks, 256, 0, stream>>>(h1, h2, nullptr, csr, rowptr, Wl1, bl1, Wr1, N, 1, nwaves);
  k_layer<<<blocks, 256, 0, stream>>>(h2, nullptr, out, csr, rowptr, Wl2, bl2, Wr2, N, 0, nwaves);
}

// Round 13
// 678.198 us; speedup vs baseline: 1.0634x; 1.0634x over previous
//
#include <hip/hip_runtime.h>

// GraphNN 3-layer weighted-mean GCN. N=100k, E=1M, d=64.
// R9: back to R7 base (512-thr persistent blocks, LDS weights padded, bf16 rows)
// + 2-node software pipelining per wave: interleaved gather chains double the
// outstanding loads (latency-bound fix), direct per-group csr loads.

static constexpr int kD = 64;
static constexpr int WPAD = 68;
typedef unsigned int uint_t;
typedef unsigned short ushort_t;

__device__ __forceinline__ float bf2f(ushort_t u) {
  return __uint_as_float(((uint_t)u) << 16);
}
__device__ __forceinline__ ushort_t f2bf(float f) {
  uint_t u = __float_as_uint(f);
  u += 0x7fffu + ((u >> 16) & 1u);  // RNE
  return (ushort_t)(u >> 16);
}

__global__ __launch_bounds__(256) void k_edge_deg(
    const int* __restrict__ col, const float* __restrict__ ew,
    float* __restrict__ deg, uint_t* __restrict__ cnt, int E) {
  int e = blockIdx.x * 256 + threadIdx.x;
  if (e >= E) return;
  int c = col[e];
  unsafeAtomicAdd(&deg[c], ew[e]);
  atomicAdd(&cnt[c], 1u);
}

__global__ __launch_bounds__(256) void k_node_pre(float* __restrict__ deg, int N) {
  int n = blockIdx.x * 256 + threadIdx.x;
  if (n >= N) return;
  float d = deg[n];
  deg[n] = (d > 0.0f) ? rsqrtf(d) : 0.0f;
}

__global__ __launch_bounds__(256) void k_scanA(
    const uint_t* __restrict__ cnt, uint_t* __restrict__ incl,
    uint_t* __restrict__ bsum, int N) {
  __shared__ uint_t s[256];
  int t = threadIdx.x;
  int i = blockIdx.x * 256 + t;
  uint_t v = (i < N) ? cnt[i] : 0u;
  s[t] = v;
  __syncthreads();
  for (int off = 1; off < 256; off <<= 1) {
    uint_t tv = (t >= off) ? s[t - off] : 0u;
    __syncthreads();
    s[t] += tv;
    __syncthreads();
  }
  if (i < N) incl[i] = s[t];
  if (t == 255) bsum[blockIdx.x] = s[255];
}

__global__ __launch_bounds__(512) void k_scanB(
    const uint_t* __restrict__ bsum, uint_t* __restrict__ boff, int nb) {
  __shared__ uint_t s[512];
  int t = threadIdx.x;
  uint_t v = (t < nb) ? bsum[t] : 0u;
  s[t] = v;
  __syncthreads();
  for (int off = 1; off < 512; off <<= 1) {
    uint_t tv = (t >= off) ? s[t - off] : 0u;
    __syncthreads();
    s[t] += tv;
    __syncthreads();
  }
  if (t < nb) boff[t] = s[t] - v;
}

__global__ __launch_bounds__(256) void k_scanC(
    const uint_t* __restrict__ incl, const uint_t* __restrict__ cnt,
    const uint_t* __restrict__ boff, uint_t* __restrict__ rowptr, int N) {
  int i = blockIdx.x * 256 + threadIdx.x;
  if (i >= N) return;
  uint_t inc = incl[i] + boff[i >> 8];
  rowptr[i] = inc - cnt[i];
  if (i == N - 1) rowptr[N] = inc;
}

__global__ __launch_bounds__(256) void k_fill(
    const int* __restrict__ row, const int* __restrict__ col,
    const float* __restrict__ ew, const float* __restrict__ dis,
    const uint_t* __restrict__ rowptr, uint_t* __restrict__ fillcnt,
    int2* __restrict__ csr, int E) {
  int e = blockIdx.x * 256 + threadIdx.x;
  if (e >= E) return;
  int c = col[e];
  int r = row[e];
  float w = dis[r] * ew[e] * dis[c];
  uint_t pos = atomicAdd(&fillcnt[c], 1u);
  csr[rowptr[c] + pos] = make_int2(r, __float_as_int(w));
}

__global__ __launch_bounds__(256) void k_cvt(
    const float* __restrict__ x, ushort_t* __restrict__ xb, int total) {
  int i = blockIdx.x * 256 + threadIdx.x;
  if (i >= total) return;
  xb[i] = f2bf(x[i]);
}

// ---------- fused layer: 2-node pipelined gather ----------
__global__ __launch_bounds__(512) void k_layer(
    const ushort_t* __restrict__ A, ushort_t* __restrict__ B16,
    float* __restrict__ Bf,
    const int2* __restrict__ csr, const uint_t* __restrict__ rowptr,
    const float* __restrict__ Wl, const float* __restrict__ bl,
    const float* __restrict__ Wr, int N, int relu, int nwaves) {
  __shared__ float sW[2 * kD * WPAD];
  __shared__ float sAgg[8][kD];
  __shared__ float sX[8][kD];
  int tid = threadIdx.x;
  int wave = tid >> 6, lane = tid & 63;
  int g = lane >> 4;
  int l16 = lane & 15;

  for (int i = tid; i < kD * 16; i += 512) {
    int r = i >> 4, c4 = i & 15;
    float4 v = reinterpret_cast<const float4*>(Wl)[i];
    float4 u = reinterpret_cast<const float4*>(Wr)[i];
    *reinterpret_cast<float4*>(&sW[r * WPAD + c4 * 4]) = v;
    *reinterpret_cast<float4*>(&sW[kD * WPAD + r * WPAD + c4 * 4]) = u;
  }
  float bias = bl[lane];
  __syncthreads();

  const float* sWl = sW + (size_t)lane * WPAD;
  const float* sWr = sW + kD * WPAD + (size_t)lane * WPAD;

  int npairs = (N + 1) >> 1;
  int gw = blockIdx.x * 8 + wave;

#define GATHER_STEP(IX, RE, RB, ACC)                                           \
    { uint_t ix = (IX);                                                        \
      bool val = ix < (RE);                                                    \
      int2 er = csr[val ? ix : (RB)];                                          \
      float ww = val ? __int_as_float(er.y) : 0.0f;                            \
      uint2 q = *reinterpret_cast<const uint2*>(A + (size_t)er.x * kD + l16 * 4); \
      ACC.x += ww * __uint_as_float(q.x << 16);                                \
      ACC.y += ww * __uint_as_float(q.x & 0xffff0000u);                        \
      ACC.z += ww * __uint_as_float(q.y << 16);                                \
      ACC.w += ww * __uint_as_float(q.y & 0xffff0000u); }

#define REDUCE_TRANSFORM(ACC, NN, DEGC)                                        \
    { ACC.x += __shfl_xor(ACC.x, 16); ACC.y += __shfl_xor(ACC.y, 16);          \
      ACC.z += __shfl_xor(ACC.z, 16); ACC.w += __shfl_xor(ACC.w, 16);          \
      ACC.x += __shfl_xor(ACC.x, 32); ACC.y += __shfl_xor(ACC.y, 32);          \
      ACC.z += __shfl_xor(ACC.z, 32); ACC.w += __shfl_xor(ACC.w, 32);          \
      float ci = ((DEGC) > 0) ? (1.0f / (float)(DEGC)) : 1.0f;                 \
      if (g == 0) {                                                            \
        *reinterpret_cast<float4*>(&sAgg[wave][l16 * 4]) =                     \
            make_float4(ACC.x * ci, ACC.y * ci, ACC.z * ci, ACC.w * ci);       \
      }                                                                        \
      sX[wave][lane] = bf2f(A[(size_t)(NN) * kD + lane]);                      \
      float o = bias;                                                          \
      _Pragma("unroll")                                                        \
      for (int k4 = 0; k4 < 16; ++k4) {                                        \
        float4 ag = *reinterpret_cast<const float4*>(&sAgg[wave][k4 * 4]);     \
        float4 xv = *reinterpret_cast<const float4*>(&sX[wave][k4 * 4]);       \
        float4 wl = *reinterpret_cast<const float4*>(&sWl[k4 * 4]);            \
        float4 wr = *reinterpret_cast<const float4*>(&sWr[k4 * 4]);            \
        o += ag.x * wl.x + ag.y * wl.y + ag.z * wl.z + ag.w * wl.w;            \
        o += xv.x * wr.x + xv.y * wr.y + xv.z * wr.z + xv.w * wr.w;            \
      }                                                                        \
      if (relu) o = fmaxf(o, 0.0f);                                            \
      if (B16) B16[(size_t)(NN) * kD + lane] = f2bf(o);                        \
      else     Bf[(size_t)(NN) * kD + lane] = o; }

  for (int pp = gw; pp < npairs; pp += nwaves) {
    int n0 = pp * 2;
    int n1 = n0 + 1;
    bool has1 = n1 < N;
    uint_t rb0 = rowptr[n0], re0 = rowptr[n0 + 1];
    uint_t rb1 = has1 ? rowptr[n1] : 0u;
    uint_t re1 = has1 ? rowptr[n1 + 1] : 0u;
    int deg0 = (int)(re0 - rb0);
    int deg1 = (int)(re1 - rb1);
    float4 acc0 = make_float4(0.f, 0.f, 0.f, 0.f);
    float4 acc1 = make_float4(0.f, 0.f, 0.f, 0.f);
    // interleaved dual-node gather: 4 independent row loads in flight
    for (uint_t i0 = rb0 + g, i1 = rb1 + g; i0 < re0 || i1 < re1; i0 += 8, i1 += 8) {
      GATHER_STEP(i0,     re0, rb0, acc0)
      GATHER_STEP(i1,     re1, rb1, acc1)
      GATHER_STEP(i0 + 4, re0, rb0, acc0)
      GATHER_STEP(i1 + 4, re1, rb1, acc1)
    }
    REDUCE_TRANSFORM(acc0, n0, deg0)
    if (has1) REDUCE_TRANSFORM(acc1, n1, deg1)
  }
#undef GATHER_STEP
#undef REDUCE_TRANSFORM
}

extern "C" void kernel_launch(void* const* d_in, const int* in_sizes, int n_in,
                              void* d_out, int out_size, void* d_ws, size_t ws_size,
                              hipStream_t stream) {
  const float* x   = (const float*)d_in[0];
  const int*   ei  = (const int*)d_in[1];
  const float* ew  = (const float*)d_in[2];
  const float* Wl0 = (const float*)d_in[3];
  const float* bl0 = (const float*)d_in[4];
  const float* Wr0 = (const float*)d_in[5];
  const float* Wl1 = (const float*)d_in[6];
  const float* bl1 = (const float*)d_in[7];
  const float* Wr1 = (const float*)d_in[8];
  const float* Wl2 = (const float*)d_in[9];
  const float* bl2 = (const float*)d_in[10];
  const float* Wr2 = (const float*)d_in[11];
  float* out = (float*)d_out;

  const int N = in_sizes[0] / kD;
  const int E = in_sizes[2];
  const int* row = ei;
  const int* col = ei + E;

  const int nb256 = (N + 255) / 256;

  char* p = (char*)d_ws;
  int2*     csr     = (int2*)p;     p += (size_t)E * sizeof(int2);
  ushort_t* xb      = (ushort_t*)p; p += (size_t)N * kD * sizeof(ushort_t);
  ushort_t* h1      = (ushort_t*)p; p += (size_t)N * kD * sizeof(ushort_t);
  ushort_t* h2      = (ushort_t*)p; p += (size_t)N * kD * sizeof(ushort_t);
  float*    deg     = (float*)p;    p += (size_t)N * sizeof(float);
  uint_t*   cnt     = (uint_t*)p;   p += (size_t)N * sizeof(uint_t);
  uint_t*   fillcnt = (uint_t*)p;   p += (size_t)N * sizeof(uint_t);
  uint_t*   rowptr  = (uint_t*)p;   p += (size_t)(N + 1) * sizeof(uint_t);
  uint_t*   incl    = (uint_t*)p;   p += (size_t)N * sizeof(uint_t);
  uint_t*   bsum    = (uint_t*)p;   p += (size_t)nb256 * sizeof(uint_t);
  uint_t*   boff    = (uint_t*)p;

  const int eb = (E + 255) / 256;

  hipMemsetAsync(deg, 0, 3 * (size_t)N * sizeof(float), stream);
  k_edge_deg<<<eb, 256, 0, stream>>>(col, ew, deg, cnt, E);
  k_node_pre<<<nb256, 256, 0, stream>>>(deg, N);
  k_scanA<<<nb256, 256, 0, stream>>>(cnt, incl, bsum, N);
  k_scanB<<<1, 512, 0, stream>>>(bsum, boff, nb256);
  k_scanC<<<nb256, 256, 0, stream>>>(incl, cnt, boff, rowptr, N);
  k_fill<<<eb, 256, 0, stream>>>(row, col, ew, deg, rowptr, fillcnt, csr, E);
  k_cvt<<<(N * kD + 255) / 256, 256, 0, stream>>>(x, xb, N * kD);

  const int blocks = 1024;            // persistent, 8 waves each
  const int nwaves = blocks * 8;
  k_layer<<<blocks, 512, 0, stream>>>(xb, h1, nullptr, csr, rowptr, Wl0, bl0, Wr0, N, 1, nwaves);
  k_layer<<<blocks, 512, 0, stream>>>(h1, h2, nullptr, csr, rowptr, Wl1, bl1, Wr1, N, 1, nwaves);
  k_layer<<<blocks, 512, 0, stream>>>(h2, nullptr, out, csr, rowptr, Wl2, bl2, Wr2, N, 0, nwaves);
}